// Round 20
// baseline (72.447 us; speedup 1.0000x reference)
//
#include <hip/hip_runtime.h>
#include <hip/hip_bf16.h>

// Shapes
#define BB 16
#define PP 64
#define NN 4096
#define DD 768
#define TT 16      // tokens per tile
#define NTILE 16   // tiles per 256-token chunk
#define VROW 772   // padded LDS row stride (f32): 772 % 32 == 4 -> bank-spread rows
#define LPS 72     // lpf p-stride (f32): 72 % 32 == 8 -> b128 writes/reads at floor

typedef __attribute__((ext_vector_type(4))) float f32x4;
typedef __attribute__((ext_vector_type(2))) float f32x2;
typedef __attribute__((ext_vector_type(8))) __bf16 bf16x8;
typedef __attribute__((ext_vector_type(2))) __bf16 bf16x2;
typedef __attribute__((ext_vector_type(4))) short s16x4;
typedef __attribute__((ext_vector_type(4))) _Float16 f16x4;

#if __has_builtin(__builtin_amdgcn_mfma_f32_16x16x16bf16_1k)
#define HAVE_K16 1
#define PSTRIDE 20
#else
#define HAVE_K16 0
#define PSTRIDE 40
#endif

__device__ __forceinline__ f32x4 mfma16(bf16x8 a, bf16x8 b, f32x4 c) {
    return __builtin_amdgcn_mfma_f32_16x16x32_bf16(a, b, c, 0, 0, 0);
}

__device__ __forceinline__ void gl_lds(const float* g, float* l) {
    __builtin_amdgcn_global_load_lds(
        (const __attribute__((address_space(1))) void*)g,
        (__attribute__((address_space(3))) void*)l, 16, 0, 0);
}

__device__ __forceinline__ short bf2s(float f) {
    __bf16 h = (__bf16)f;
    return *(short*)&h;
}

#define S_WAITCNT_VM(N) asm volatile("s_waitcnt vmcnt(" #N ")" ::: "memory")
#define BARRIER() do { __builtin_amdgcn_s_barrier(); asm volatile("" ::: "memory"); } while (0)
// LDS-only barrier: drains ds ops, NOT vmcnt (DMA prefetch stays in flight).
#define LDS_BARRIER() do { asm volatile("s_waitcnt lgkmcnt(0)" ::: "memory"); \
                           __builtin_amdgcn_s_barrier(); \
                           __builtin_amdgcn_sched_barrier(0); } while (0)

// LDS layout (bytes):
//   [0,      98816)  vstage[2][16][772] f32  (row-padded; NO swizzle anywhere)
//   [98816, 135680)  lpf[8][16][LPS] f32     (QK^T partials, [w][token][p] - p contiguous)
//   [135680,140800)  pbuf[64][PSTRIDE] bf16  (P tile [p][token])
//   [140800,141568)  mrun/lrun/rsc [64] f32 each
#define SM_BYTES 141568

// PV output-column remap (R19): MFMA #df's B-col l15 supplies d = DMAP(l15,df)
// -> V reads per k-row are one f32x4 + one f32x2. Bijective; epilogue matches.
#define DMAP(l, df) ((df) < 4 ? ((l) * 4 + (df)) : (64 + (l) * 2 + ((df) - 4)))

// ---------------------------------------------------------------------------
// Flash: per (b, 256-token chunk), stream 16 tiles of 16 tokens x 768 d (f32)
// through LDS ONCE; per tile: QK^T -> online softmax -> PV into reg-resident O.
// grid 256 = 16 b x 16 chunks; block 512 (8 waves).
// This round: lpf transposed to p-contiguous (b128 writes/reads), softmax
// remapped to vector reads, stats/rsc vectorized.
// ---------------------------------------------------------------------------
__global__ __launch_bounds__(512, 2) void k_flash(const float* __restrict__ x,
                                                  const float* __restrict__ q,
                                                  float* __restrict__ statm,
                                                  float* __restrict__ statl,
                                                  _Float16* __restrict__ part) {
    const int b  = blockIdx.x >> 4;
    const int sp = blockIdx.x & 15;
    const int n0 = sp * 256;

    __shared__ __align__(16) char smem[SM_BYTES];
    float*  vst  = (float*)smem;
    float*  lpf  = (float*)(smem + 98816);
    __bf16* pbuf = (__bf16*)(smem + 135680);
    float*  mrun = (float*)(smem + 140800);
    float*  lrun = (float*)(smem + 141056);
    float*  rsc  = (float*)(smem + 141312);

    const int t = threadIdx.x;
    const int w = t >> 6, lane = t & 63;
    const int l15 = lane & 15, hi = lane >> 4;

    const size_t xbase = (size_t)b * NN + n0;
    const size_t qbase = (size_t)b * PP;

    // ---- Q-fragment preload: wave w owns kd-slice [w*96, w*96+96) ----
    bf16x8 qf[4][3];
    #pragma unroll
    for (int am = 0; am < 4; ++am)
        #pragma unroll
        for (int s = 0; s < 3; ++s) {
            const size_t off = (qbase + am * 16 + l15) * DD + w * 96 + s * 32 + hi * 8;
            const float4 a = *(const float4*)&q[off];
            const float4 c = *(const float4*)&q[off + 4];
            qf[am][s] = (bf16x8){(__bf16)a.x, (__bf16)a.y, (__bf16)a.z, (__bf16)a.w,
                                 (__bf16)c.x, (__bf16)c.y, (__bf16)c.z, (__bf16)c.w};
        }

#if !HAVE_K16
    for (int i = t; i < 64 * PSTRIDE / 2; i += 512) ((unsigned*)pbuf)[i] = 0;
#endif
    if (t < 64) { mrun[t] = -1e30f; lrun[t] = 0.f; }

    // O accumulator: wave w owns d-slice [w*96, w*96+96): 4 p-frags x 6 d-frags.
    f32x4 O[4][6] = {};

    // Linear staging: issue idx (0..47) covers row idx/3, 256-f32 third idx%3.
#define STAGE(bufi, tile) do {                                                \
        float* vb_ = vst + (bufi) * (TT * VROW);                              \
        _Pragma("unroll")                                                     \
        for (int i_ = 0; i_ < 6; ++i_) {                                      \
            const int idx_ = w * 6 + i_;                                      \
            const int r_ = idx_ / 3, c_ = idx_ % 3;                           \
            gl_lds(&x[(xbase + (size_t)(tile) * TT + r_) * DD + c_ * 256 + lane * 4], \
                   vb_ + r_ * VROW + c_ * 256);                               \
        }                                                                     \
    } while (0)

    STAGE(0, 0);

    const float scale = 0.036084391824351615f;  // 768^-0.5
    // softmax mapping: pq = p-quad (p = pq*4+c), tok = token, half = w-half.
    // All shfl partners (half: xor 1, tok: xor 2/4/8/16) are within one wave.
    const int pq   = t >> 5;
    const int tok  = (t >> 1) & 15;
    const int half = t & 1;

    for (int tile = 0; tile < NTILE; ++tile) {
        if (tile < NTILE - 1) { STAGE((tile + 1) & 1, tile + 1); S_WAITCNT_VM(6); }
        else                  { S_WAITCNT_VM(0); }
        BARRIER();
        const float* vb = vst + (tile & 1) * (TT * VROW);

        // ---- QK^T: wave w: kd in {w*96, +32, +64}, all 4 p-frags ----
        f32x4 acc[4] = {};
        #pragma unroll
        for (int s = 0; s < 3; ++s) {
            const int g0 = w * 24 + s * 8 + hi * 2;      // f32x4 granule index
            const float* kp = vb + l15 * VROW + g0 * 4;
            const f32x4 lo = *(const f32x4*)kp;
            const f32x4 hg = *(const f32x4*)(kp + 4);
            const bf16x8 kf = {(__bf16)lo[0], (__bf16)lo[1], (__bf16)lo[2], (__bf16)lo[3],
                               (__bf16)hg[0], (__bf16)hg[1], (__bf16)hg[2], (__bf16)hg[3]};
            #pragma unroll
            for (int am = 0; am < 4; ++am) acc[am] = mfma16(qf[am][s], kf, acc[am]);
        }
        // C-fragment rows (p = am*16+hi*4+j) are contiguous in j -> b128 writes.
        // lpf[w][token=l15][p]; bank audit: (w*16+l15)*72 + am*16 + hi*4 -> 8
        // start-quads x 8 lanes = exact b128 floor, conflict-free.
        #pragma unroll
        for (int am = 0; am < 4; ++am)
            *(f32x4*)&lpf[(w * 16 + l15) * LPS + am * 16 + hi * 4] = acc[am];
        LDS_BARRIER();

        // ---- online softmax: thread = (pq, tok, half); f32x4 over p ----
        f32x4 s4 = {0.f, 0.f, 0.f, 0.f};
        #pragma unroll
        for (int i = 0; i < 4; ++i) {
            const int wi = half * 4 + i;
            s4 += *(const f32x4*)&lpf[(wi * 16 + tok) * LPS + pq * 4];
        }
        // combine the two w-halves (adjacent lanes)
        #pragma unroll
        for (int c = 0; c < 4; ++c) s4[c] += __shfl_xor(s4[c], 1);
        #pragma unroll
        for (int c = 0; c < 4; ++c) s4[c] *= scale;
        // per-p (per-component) max over 16 tokens (lane bits 1..4)
        f32x4 mt4 = s4;
        #pragma unroll
        for (int off = 2; off <= 16; off <<= 1)
            #pragma unroll
            for (int c = 0; c < 4; ++c) mt4[c] = fmaxf(mt4[c], __shfl_xor(mt4[c], off));
        const f32x4 mo4 = *(const f32x4*)&mrun[pq * 4];
        f32x4 mn4, e4;
        #pragma unroll
        for (int c = 0; c < 4; ++c) {
            mn4[c] = fmaxf(mo4[c], mt4[c]);
            e4[c]  = __expf(s4[c] - mn4[c]);
        }
        f32x4 ls4 = e4;
        #pragma unroll
        for (int off = 2; off <= 16; off <<= 1)
            #pragma unroll
            for (int c = 0; c < 4; ++c) ls4[c] += __shfl_xor(ls4[c], off);
        if (half == 0) {   // halves duplicate e4; one writer per (p, tok)
            #pragma unroll
            for (int c = 0; c < 4; ++c)
                pbuf[(pq * 4 + c) * PSTRIDE + tok] = (__bf16)e4[c];
        }
        if ((lane & 31) == 0) {   // tok==0 && half==0: one stats writer per pq
            const int p0 = pq * 4;
            const f32x4 lo = *(const f32x4*)&lrun[p0];
            f32x4 f4;
            #pragma unroll
            for (int c = 0; c < 4; ++c) f4[c] = __expf(mo4[c] - mn4[c]);  // ==1.0 if no growth
            f32x4 ln;
            #pragma unroll
            for (int c = 0; c < 4; ++c) ln[c] = lo[c] * f4[c] + ls4[c];
            *(f32x4*)&lrun[p0] = ln;
            *(f32x4*)&mrun[p0] = mn4;
            *(f32x4*)&rsc[p0]  = f4;
        }
        LDS_BARRIER();

        // ---- O-rescale (vector rsc reads) ----
        #pragma unroll
        for (int am = 0; am < 4; ++am) {
            const f32x4 f4 = *(const f32x4*)&rsc[am * 16 + hi * 4];
            #pragma unroll
            for (int df = 0; df < 6; ++df)
                #pragma unroll
                for (int j = 0; j < 4; ++j) O[am][df][j] *= f4[j];
        }

#if HAVE_K16
        // ---- PV via K=16 MFMA, vectorized V reads (DMAP remap) ----
        s16x4 pf[4];
        #pragma unroll
        for (int am = 0; am < 4; ++am)
            pf[am] = *(const s16x4*)&pbuf[(am * 16 + l15) * PSTRIDE + hi * 4];
        f32x4 va[4];
        f32x2 vc[4];
        #pragma unroll
        for (int i = 0; i < 4; ++i) {
            const float* g0 = vb + (hi * 4 + i) * VROW + w * 96;
            va[i] = *(const f32x4*)(g0 + l15 * 4);
            vc[i] = *(const f32x2*)(g0 + 64 + l15 * 2);
        }
        #pragma unroll
        for (int df = 0; df < 4; ++df) {
            s16x4 vfr;
            #pragma unroll
            for (int i = 0; i < 4; ++i) vfr[i] = bf2s(va[i][df]);
            #pragma unroll
            for (int am = 0; am < 4; ++am)
                O[am][df] = __builtin_amdgcn_mfma_f32_16x16x16bf16_1k(pf[am], vfr, O[am][df], 0, 0, 0);
        }
        #pragma unroll
        for (int df = 4; df < 6; ++df) {
            s16x4 vfr;
            #pragma unroll
            for (int i = 0; i < 4; ++i) vfr[i] = bf2s(vc[i][df - 4]);
            #pragma unroll
            for (int am = 0; am < 4; ++am)
                O[am][df] = __builtin_amdgcn_mfma_f32_16x16x16bf16_1k(pf[am], vfr, O[am][df], 0, 0, 0);
        }
#else
        // ---- fallback: K=32 MFMA (zero-padded upper half), DMAP-consistent ----
        bf16x8 pf[4];
        #pragma unroll
        for (int am = 0; am < 4; ++am)
            pf[am] = *(const bf16x8*)&pbuf[(am * 16 + l15) * PSTRIDE + hi * 8];
        #pragma unroll
        for (int df = 0; df < 6; ++df) {
            float vf[8];
            #pragma unroll
            for (int i = 0; i < 8; ++i) {
                const int k_ = (hi * 8 + i) & 15;
                vf[i] = vb[k_ * VROW + w * 96 + DMAP(l15, df)];
            }
            const bf16x8 vfr = {(__bf16)vf[0], (__bf16)vf[1], (__bf16)vf[2], (__bf16)vf[3],
                                (__bf16)vf[4], (__bf16)vf[5], (__bf16)vf[6], (__bf16)vf[7]};
            #pragma unroll
            for (int am = 0; am < 4; ++am) O[am][df] = mfma16(pf[am], vfr, O[am][df]);
        }
#endif
        LDS_BARRIER();
    }

    // ---- epilogue: stats + unnormalized O to part (f16), DMAP d-indexing ----
    if (t < 64) {
        const size_t si = ((size_t)b * 16 + sp) * 64 + t;
        statm[si] = mrun[t];
        statl[si] = lrun[t];
    }
    #pragma unroll
    for (int am = 0; am < 4; ++am)
        #pragma unroll
        for (int j = 0; j < 4; ++j) {
            const int p = am * 16 + hi * 4 + j;
            #pragma unroll
            for (int df = 0; df < 6; ++df) {
                const int d_ = w * 96 + DMAP(l15, df);
                part[(((size_t)sp * BB + b) * PP + p) * DD + d_] = (_Float16)O[am][df][j];
            }
        }
}

// ---------------------------------------------------------------------------
// Combine: out[b,p,d] = sum_sp exp(m_sp - M) * part[sp,b,p,d] / D,
//          D = sum_c exp(m_c - M) * l_c.
// ---------------------------------------------------------------------------
__global__ __launch_bounds__(256) void k_combine(const _Float16* __restrict__ part,
                                                 const float* __restrict__ statm,
                                                 const float* __restrict__ statl,
                                                 float* __restrict__ out) {
    const size_t idx = (size_t)blockIdx.x * 256 + threadIdx.x;  // f32x4 units
    const size_t e = idx * 4;
    const int bp = (int)(e / DD);
    const int b = bp >> 6, p = bp & 63;

    float M = -1e30f;
    #pragma unroll
    for (int c = 0; c < 16; ++c) M = fmaxf(M, statm[((size_t)b * 16 + c) * 64 + p]);
    float Ee[16];
    float D = 0.f;
    #pragma unroll
    for (int c = 0; c < 16; ++c) {
        Ee[c] = __expf(statm[((size_t)b * 16 + c) * 64 + p] - M);
        D += Ee[c] * statl[((size_t)b * 16 + c) * 64 + p];
    }
    const float inv = 1.f / D;

    float4 v = {0.f, 0.f, 0.f, 0.f};
    #pragma unroll
    for (int c = 0; c < 16; ++c) {
        const f16x4 h = *(const f16x4*)&part[(size_t)c * ((size_t)BB * PP * DD) + e];
        v.x += Ee[c] * (float)h[0];
        v.y += Ee[c] * (float)h[1];
        v.z += Ee[c] * (float)h[2];
        v.w += Ee[c] * (float)h[3];
    }
    v.x *= inv; v.y *= inv; v.z *= inv; v.w *= inv;
    *(float4*)&out[e] = v;
}

extern "C" void kernel_launch(void* const* d_in, const int* in_sizes, int n_in,
                              void* d_out, int out_size, void* d_ws, size_t ws_size,
                              hipStream_t stream) {
    const float* x = (const float*)d_in[0];   // [16, 4096, 768]
    const float* q = (const float*)d_in[1];   // [16, 64, 768]
    float* out = (float*)d_out;               // [16, 64, 768]

    char* ws = (char*)d_ws;
    float*     statm = (float*)ws;                       // 64 KB [16][16][64]
    float*     statl = (float*)(ws + 65536);             // 64 KB
    _Float16*  part  = (_Float16*)(ws + 131072);         // 24 MB [16][16][64][768]

    hipLaunchKernelGGL(k_flash,   dim3(256), dim3(512), 0, stream, x, q, statm, statl, part);
    hipLaunchKernelGGL(k_combine, dim3(768), dim3(256), 0, stream, part, statm, statl, out);
}

// Round 21
// 59.630 us; speedup vs baseline: 1.2149x; 1.2149x over previous
//
#include <hip/hip_runtime.h>
#include <hip/hip_bf16.h>

// Shapes
#define BB 16
#define PP 64
#define NN 4096
#define DD 768
#define TT 16      // tokens per tile
#define NTILE 16   // tiles per 256-token chunk
#define VROW 772   // padded LDS row stride (f32): 772 % 32 == 4 -> bank-spread rows

typedef __attribute__((ext_vector_type(4))) float f32x4;
typedef __attribute__((ext_vector_type(2))) float f32x2;
typedef __attribute__((ext_vector_type(8))) __bf16 bf16x8;
typedef __attribute__((ext_vector_type(2))) __bf16 bf16x2;
typedef __attribute__((ext_vector_type(4))) short s16x4;
typedef __attribute__((ext_vector_type(4))) _Float16 f16x4;

#if __has_builtin(__builtin_amdgcn_mfma_f32_16x16x16bf16_1k)
#define HAVE_K16 1
#define PSTRIDE 20
#else
#define HAVE_K16 0
#define PSTRIDE 40
#endif

__device__ __forceinline__ f32x4 mfma16(bf16x8 a, bf16x8 b, f32x4 c) {
    return __builtin_amdgcn_mfma_f32_16x16x32_bf16(a, b, c, 0, 0, 0);
}

__device__ __forceinline__ void gl_lds(const float* g, float* l) {
    __builtin_amdgcn_global_load_lds(
        (const __attribute__((address_space(1))) void*)g,
        (__attribute__((address_space(3))) void*)l, 16, 0, 0);
}

__device__ __forceinline__ short bf2s(float f) {
    __bf16 h = (__bf16)f;
    return *(short*)&h;
}

#define S_WAITCNT_VM(N) asm volatile("s_waitcnt vmcnt(" #N ")" ::: "memory")
#define BARRIER() do { __builtin_amdgcn_s_barrier(); asm volatile("" ::: "memory"); } while (0)
// LDS-only barrier: drains ds ops, NOT vmcnt (DMA prefetch stays in flight).
#define LDS_BARRIER() do { asm volatile("s_waitcnt lgkmcnt(0)" ::: "memory"); \
                           __builtin_amdgcn_s_barrier(); \
                           __builtin_amdgcn_sched_barrier(0); } while (0)

// LDS layout (bytes):
//   [0,      98816)  vstage[2][16][772] f32  (row-padded; NO swizzle anywhere)
//   [98816, 135680)  lpf[8][64][18] f32      (QK^T kd-slice partials)
//   [135680,140800)  pbuf[64][PSTRIDE] bf16  (P tile)
//   [140800,141568)  mrun/lrun/rsc [64] f32 each
#define SM_BYTES 141568

// PV output-column remap: MFMA #df's B-col l15 supplies d = DMAP(l15, df).
// Chosen so each thread's V reads per k-row are ONE f32x4 (df 0..3, at
// l15*4) + ONE f32x2 (df 4..5, at 64+l15*2): 8 LDS reads/lane/tile instead
// of 24 scalar b32. Bijective onto [w*96, w*96+96); epilogue uses same map.
#define DMAP(l, df) ((df) < 4 ? ((l) * 4 + (df)) : (64 + (l) * 2 + ((df) - 4)))

// ---------------------------------------------------------------------------
// Flash: per (b, 256-token chunk), stream 16 tiles of 16 tokens x 768 d (f32)
// through LDS ONCE; per tile: QK^T -> online softmax -> PV into reg-resident O.
// grid 256 = 16 b x 16 chunks; block 512 (8 waves).
// FINAL champion (R19, 59.6 us): TT=16, double-buffered gl_lds staging with
// counted vmcnt(6), K16 PV with DMAP-vectorized V reads, linear staging.
// R20's softmax remap regressed (72.4); R11-R18 variants all null/worse.
// ---------------------------------------------------------------------------
__global__ __launch_bounds__(512, 2) void k_flash(const float* __restrict__ x,
                                                  const float* __restrict__ q,
                                                  float* __restrict__ statm,
                                                  float* __restrict__ statl,
                                                  _Float16* __restrict__ part) {
    const int b  = blockIdx.x >> 4;
    const int sp = blockIdx.x & 15;
    const int n0 = sp * 256;

    __shared__ __align__(16) char smem[SM_BYTES];
    float*  vst  = (float*)smem;
    float*  lpf  = (float*)(smem + 98816);
    __bf16* pbuf = (__bf16*)(smem + 135680);
    float*  mrun = (float*)(smem + 140800);
    float*  lrun = (float*)(smem + 141056);
    float*  rsc  = (float*)(smem + 141312);

    const int t = threadIdx.x;
    const int w = t >> 6, lane = t & 63;
    const int l15 = lane & 15, hi = lane >> 4;

    const size_t xbase = (size_t)b * NN + n0;
    const size_t qbase = (size_t)b * PP;

    // ---- Q-fragment preload: wave w owns kd-slice [w*96, w*96+96) ----
    bf16x8 qf[4][3];
    #pragma unroll
    for (int am = 0; am < 4; ++am)
        #pragma unroll
        for (int s = 0; s < 3; ++s) {
            const size_t off = (qbase + am * 16 + l15) * DD + w * 96 + s * 32 + hi * 8;
            const float4 a = *(const float4*)&q[off];
            const float4 c = *(const float4*)&q[off + 4];
            qf[am][s] = (bf16x8){(__bf16)a.x, (__bf16)a.y, (__bf16)a.z, (__bf16)a.w,
                                 (__bf16)c.x, (__bf16)c.y, (__bf16)c.z, (__bf16)c.w};
        }

#if !HAVE_K16
    for (int i = t; i < 64 * PSTRIDE / 2; i += 512) ((unsigned*)pbuf)[i] = 0;
#endif
    if (t < 64) { mrun[t] = -1e30f; lrun[t] = 0.f; }

    // O accumulator: wave w owns d-slice [w*96, w*96+96): 4 p-frags x 6 d-frags.
    f32x4 O[4][6] = {};

    // Linear staging: issue idx (0..47) covers row idx/3, 256-f32 third idx%3.
#define STAGE(bufi, tile) do {                                                \
        float* vb_ = vst + (bufi) * (TT * VROW);                              \
        _Pragma("unroll")                                                     \
        for (int i_ = 0; i_ < 6; ++i_) {                                      \
            const int idx_ = w * 6 + i_;                                      \
            const int r_ = idx_ / 3, c_ = idx_ % 3;                           \
            gl_lds(&x[(xbase + (size_t)(tile) * TT + r_) * DD + c_ * 256 + lane * 4], \
                   vb_ + r_ * VROW + c_ * 256);                               \
        }                                                                     \
    } while (0)

    STAGE(0, 0);

    const float scale = 0.036084391824351615f;  // 768^-0.5
    const int p_  = t >> 3;      // softmax row
    const int np_ = t & 7;       // softmax n-pair

    for (int tile = 0; tile < NTILE; ++tile) {
        if (tile < NTILE - 1) { STAGE((tile + 1) & 1, tile + 1); S_WAITCNT_VM(6); }
        else                  { S_WAITCNT_VM(0); }
        BARRIER();
        const float* vb = vst + (tile & 1) * (TT * VROW);

        // ---- QK^T: wave w: kd in {w*96, +32, +64}, all 4 p-frags ----
        f32x4 acc[4] = {};
        #pragma unroll
        for (int s = 0; s < 3; ++s) {
            const int g0 = w * 24 + s * 8 + hi * 2;      // f32x4 granule index
            const float* kp = vb + l15 * VROW + g0 * 4;
            const f32x4 lo = *(const f32x4*)kp;
            const f32x4 hg = *(const f32x4*)(kp + 4);
            const bf16x8 kf = {(__bf16)lo[0], (__bf16)lo[1], (__bf16)lo[2], (__bf16)lo[3],
                               (__bf16)hg[0], (__bf16)hg[1], (__bf16)hg[2], (__bf16)hg[3]};
            #pragma unroll
            for (int am = 0; am < 4; ++am) acc[am] = mfma16(qf[am][s], kf, acc[am]);
        }
        #pragma unroll
        for (int am = 0; am < 4; ++am)
            #pragma unroll
            for (int j = 0; j < 4; ++j)
                lpf[(w * 64 + am * 16 + hi * 4 + j) * 18 + l15] = acc[am][j];
        LDS_BARRIER();

        // ---- online softmax: 8 threads per p-row, 2 tokens each ----
        float s0 = 0.f, s1 = 0.f;
        #pragma unroll
        for (int sl = 0; sl < 8; ++sl) {
            const float2 v2 = *(const float2*)&lpf[(sl * 64 + p_) * 18 + 2 * np_];
            s0 += v2.x; s1 += v2.y;
        }
        s0 *= scale; s1 *= scale;
        float mt = fmaxf(s0, s1);
        mt = fmaxf(mt, __shfl_xor(mt, 1));
        mt = fmaxf(mt, __shfl_xor(mt, 2));
        mt = fmaxf(mt, __shfl_xor(mt, 4));
        const float mo = mrun[p_];
        const float mn = fmaxf(mo, mt);
        const float e0 = __expf(s0 - mn), e1 = __expf(s1 - mn);
        float lsum = e0 + e1;
        lsum += __shfl_xor(lsum, 1);
        lsum += __shfl_xor(lsum, 2);
        lsum += __shfl_xor(lsum, 4);
        *(bf16x2*)&pbuf[p_ * PSTRIDE + 2 * np_] = (bf16x2){(__bf16)e0, (__bf16)e1};
        if (np_ == 0) {
            const float f = __expf(mo - mn);   // == 1.0 exactly when mt <= mo
            lrun[p_] = lrun[p_] * f + lsum;
            mrun[p_] = mn;
            rsc[p_]  = f;
        }
        LDS_BARRIER();

        // ---- O-rescale ----
        #pragma unroll
        for (int am = 0; am < 4; ++am)
            #pragma unroll
            for (int j = 0; j < 4; ++j) {
                const float f = rsc[am * 16 + hi * 4 + j];
                #pragma unroll
                for (int df = 0; df < 6; ++df) O[am][df][j] *= f;
            }

#if HAVE_K16
        // ---- PV via K=16 MFMA, vectorized V reads (DMAP remap) ----
        s16x4 pf[4];
        #pragma unroll
        for (int am = 0; am < 4; ++am)
            pf[am] = *(const s16x4*)&pbuf[(am * 16 + l15) * PSTRIDE + hi * 4];
        // per k-row (k = hi*4 + i): one f32x4 (d = w*96 + l15*4 + 0..3) and
        // one f32x2 (d = w*96 + 64 + l15*2 + 0..1). Bank-audited: both at
        // the structural minimum (8/bank b128, 4/bank b64), conflict-free.
        f32x4 va[4];
        f32x2 vc[4];
        #pragma unroll
        for (int i = 0; i < 4; ++i) {
            const float* g0 = vb + (hi * 4 + i) * VROW + w * 96;
            va[i] = *(const f32x4*)(g0 + l15 * 4);
            vc[i] = *(const f32x2*)(g0 + 64 + l15 * 2);
        }
        #pragma unroll
        for (int df = 0; df < 4; ++df) {
            s16x4 vfr;
            #pragma unroll
            for (int i = 0; i < 4; ++i) vfr[i] = bf2s(va[i][df]);
            #pragma unroll
            for (int am = 0; am < 4; ++am)
                O[am][df] = __builtin_amdgcn_mfma_f32_16x16x16bf16_1k(pf[am], vfr, O[am][df], 0, 0, 0);
        }
        #pragma unroll
        for (int df = 4; df < 6; ++df) {
            s16x4 vfr;
            #pragma unroll
            for (int i = 0; i < 4; ++i) vfr[i] = bf2s(vc[i][df - 4]);
            #pragma unroll
            for (int am = 0; am < 4; ++am)
                O[am][df] = __builtin_amdgcn_mfma_f32_16x16x16bf16_1k(pf[am], vfr, O[am][df], 0, 0, 0);
        }
#else
        // ---- fallback: K=32 MFMA (zero-padded upper half), DMAP-consistent ----
        bf16x8 pf[4];
        #pragma unroll
        for (int am = 0; am < 4; ++am)
            pf[am] = *(const bf16x8*)&pbuf[(am * 16 + l15) * PSTRIDE + hi * 8];
        #pragma unroll
        for (int df = 0; df < 6; ++df) {
            float vf[8];
            #pragma unroll
            for (int i = 0; i < 8; ++i) {
                const int k_ = (hi * 8 + i) & 15;
                vf[i] = vb[k_ * VROW + w * 96 + DMAP(l15, df)];
            }
            const bf16x8 vfr = {(__bf16)vf[0], (__bf16)vf[1], (__bf16)vf[2], (__bf16)vf[3],
                                (__bf16)vf[4], (__bf16)vf[5], (__bf16)vf[6], (__bf16)vf[7]};
            #pragma unroll
            for (int am = 0; am < 4; ++am) O[am][df] = mfma16(pf[am], vfr, O[am][df]);
        }
#endif
        LDS_BARRIER();
    }

    // ---- epilogue: stats + unnormalized O to part (f16), DMAP d-indexing ----
    if (t < 64) {
        const size_t si = ((size_t)b * 16 + sp) * 64 + t;
        statm[si] = mrun[t];
        statl[si] = lrun[t];
    }
    #pragma unroll
    for (int am = 0; am < 4; ++am)
        #pragma unroll
        for (int j = 0; j < 4; ++j) {
            const int p = am * 16 + hi * 4 + j;
            #pragma unroll
            for (int df = 0; df < 6; ++df) {
                const int d_ = w * 96 + DMAP(l15, df);
                part[(((size_t)sp * BB + b) * PP + p) * DD + d_] = (_Float16)O[am][df][j];
            }
        }
}

// ---------------------------------------------------------------------------
// Combine: out[b,p,d] = sum_sp exp(m_sp - M) * part[sp,b,p,d] / D,
//          D = sum_c exp(m_c - M) * l_c.
// ---------------------------------------------------------------------------
__global__ __launch_bounds__(256) void k_combine(const _Float16* __restrict__ part,
                                                 const float* __restrict__ statm,
                                                 const float* __restrict__ statl,
                                                 float* __restrict__ out) {
    const size_t idx = (size_t)blockIdx.x * 256 + threadIdx.x;  // f32x4 units
    const size_t e = idx * 4;
    const int bp = (int)(e / DD);
    const int b = bp >> 6, p = bp & 63;

    float M = -1e30f;
    #pragma unroll
    for (int c = 0; c < 16; ++c) M = fmaxf(M, statm[((size_t)b * 16 + c) * 64 + p]);
    float Ee[16];
    float D = 0.f;
    #pragma unroll
    for (int c = 0; c < 16; ++c) {
        Ee[c] = __expf(statm[((size_t)b * 16 + c) * 64 + p] - M);
        D += Ee[c] * statl[((size_t)b * 16 + c) * 64 + p];
    }
    const float inv = 1.f / D;

    float4 v = {0.f, 0.f, 0.f, 0.f};
    #pragma unroll
    for (int c = 0; c < 16; ++c) {
        const f16x4 h = *(const f16x4*)&part[(size_t)c * ((size_t)BB * PP * DD) + e];
        v.x += Ee[c] * (float)h[0];
        v.y += Ee[c] * (float)h[1];
        v.z += Ee[c] * (float)h[2];
        v.w += Ee[c] * (float)h[3];
    }
    v.x *= inv; v.y *= inv; v.z *= inv; v.w *= inv;
    *(float4*)&out[e] = v;
}

extern "C" void kernel_launch(void* const* d_in, const int* in_sizes, int n_in,
                              void* d_out, int out_size, void* d_ws, size_t ws_size,
                              hipStream_t stream) {
    const float* x = (const float*)d_in[0];   // [16, 4096, 768]
    const float* q = (const float*)d_in[1];   // [16, 64, 768]
    float* out = (float*)d_out;               // [16, 64, 768]

    char* ws = (char*)d_ws;
    float*     statm = (float*)ws;                       // 64 KB [16][16][64]
    float*     statl = (float*)(ws + 65536);             // 64 KB
    _Float16*  part  = (_Float16*)(ws + 131072);         // 24 MB [16][16][64][768]

    hipLaunchKernelGGL(k_flash,   dim3(256), dim3(512), 0, stream, x, q, statm, statl, part);
    hipLaunchKernelGGL(k_combine, dim3(768), dim3(256), 0, stream, part, statm, statl, out);
}

// Round 22
// 59.579 us; speedup vs baseline: 1.2160x; 1.0009x over previous
//
#include <hip/hip_runtime.h>
#include <hip/hip_bf16.h>

// Shapes
#define BB 16
#define PP 64
#define NN 4096
#define DD 768
#define TT 16      // tokens per tile
#define NTILE 16   // tiles per 256-token chunk
#define VROW 772   // padded LDS row stride (f32): 772 % 32 == 4 -> bank-spread rows

typedef __attribute__((ext_vector_type(4))) float f32x4;
typedef __attribute__((ext_vector_type(2))) float f32x2;
typedef __attribute__((ext_vector_type(8))) __bf16 bf16x8;
typedef __attribute__((ext_vector_type(2))) __bf16 bf16x2;
typedef __attribute__((ext_vector_type(4))) short s16x4;
typedef __attribute__((ext_vector_type(4))) _Float16 f16x4;

#if __has_builtin(__builtin_amdgcn_mfma_f32_16x16x16bf16_1k)
#define HAVE_K16 1
#define PSTRIDE 20
#else
#define HAVE_K16 0
#define PSTRIDE 40
#endif

__device__ __forceinline__ f32x4 mfma16(bf16x8 a, bf16x8 b, f32x4 c) {
    return __builtin_amdgcn_mfma_f32_16x16x32_bf16(a, b, c, 0, 0, 0);
}

__device__ __forceinline__ void gl_lds(const float* g, float* l) {
    __builtin_amdgcn_global_load_lds(
        (const __attribute__((address_space(1))) void*)g,
        (__attribute__((address_space(3))) void*)l, 16, 0, 0);
}

__device__ __forceinline__ short bf2s(float f) {
    __bf16 h = (__bf16)f;
    return *(short*)&h;
}

#define S_WAITCNT_VM(N) asm volatile("s_waitcnt vmcnt(" #N ")" ::: "memory")
#define BARRIER() do { __builtin_amdgcn_s_barrier(); asm volatile("" ::: "memory"); } while (0)
// LDS-only barrier: drains ds ops, NOT vmcnt (DMA prefetch stays in flight).
#define LDS_BARRIER() do { asm volatile("s_waitcnt lgkmcnt(0)" ::: "memory"); \
                           __builtin_amdgcn_s_barrier(); \
                           __builtin_amdgcn_sched_barrier(0); } while (0)

// LDS layout (bytes):
//   [0,      98816)  vstage[2][16][772] f32  (row-padded; NO swizzle anywhere)
//   [98816, 135680)  lpf[8][64][18] f32      (QK^T kd-slice partials)
//   [135680,140800)  pbuf[64][PSTRIDE] bf16  (P tile)
//   [140800,141568)  mrun/lrun/rsc [64] f32 each (rsc 16B-aligned for f32x4)
#define SM_BYTES 141568

// PV output-column remap: MFMA #df's B-col l15 supplies d = DMAP(l15, df).
// V reads per k-row: ONE f32x4 (df 0..3) + ONE f32x2 (df 4..5). Bijective
// onto [w*96, w*96+96); epilogue uses the same map.
#define DMAP(l, df) ((df) < 4 ? ((l) * 4 + (df)) : (64 + (l) * 2 + ((df) - 4)))

// ---------------------------------------------------------------------------
// Flash: per (b, 256-token chunk), stream 16 tiles of 16 tokens x 768 d (f32)
// through LDS ONCE; per tile: QK^T -> online softmax -> PV into reg-resident O.
// grid 256 = 16 b x 16 chunks; block 512 (8 waves).
// Champion (R19, 59.6 us) + one micro-change: explicit f32x4 rsc load in
// O-rescale (16 scalar b32 -> 4 b128 if the compiler wasn't merging).
// ---------------------------------------------------------------------------
__global__ __launch_bounds__(512, 2) void k_flash(const float* __restrict__ x,
                                                  const float* __restrict__ q,
                                                  float* __restrict__ statm,
                                                  float* __restrict__ statl,
                                                  _Float16* __restrict__ part) {
    const int b  = blockIdx.x >> 4;
    const int sp = blockIdx.x & 15;
    const int n0 = sp * 256;

    __shared__ __align__(16) char smem[SM_BYTES];
    float*  vst  = (float*)smem;
    float*  lpf  = (float*)(smem + 98816);
    __bf16* pbuf = (__bf16*)(smem + 135680);
    float*  mrun = (float*)(smem + 140800);
    float*  lrun = (float*)(smem + 141056);
    float*  rsc  = (float*)(smem + 141312);

    const int t = threadIdx.x;
    const int w = t >> 6, lane = t & 63;
    const int l15 = lane & 15, hi = lane >> 4;

    const size_t xbase = (size_t)b * NN + n0;
    const size_t qbase = (size_t)b * PP;

    // ---- Q-fragment preload: wave w owns kd-slice [w*96, w*96+96) ----
    bf16x8 qf[4][3];
    #pragma unroll
    for (int am = 0; am < 4; ++am)
        #pragma unroll
        for (int s = 0; s < 3; ++s) {
            const size_t off = (qbase + am * 16 + l15) * DD + w * 96 + s * 32 + hi * 8;
            const float4 a = *(const float4*)&q[off];
            const float4 c = *(const float4*)&q[off + 4];
            qf[am][s] = (bf16x8){(__bf16)a.x, (__bf16)a.y, (__bf16)a.z, (__bf16)a.w,
                                 (__bf16)c.x, (__bf16)c.y, (__bf16)c.z, (__bf16)c.w};
        }

#if !HAVE_K16
    for (int i = t; i < 64 * PSTRIDE / 2; i += 512) ((unsigned*)pbuf)[i] = 0;
#endif
    if (t < 64) { mrun[t] = -1e30f; lrun[t] = 0.f; }

    // O accumulator: wave w owns d-slice [w*96, w*96+96): 4 p-frags x 6 d-frags.
    f32x4 O[4][6] = {};

    // Linear staging: issue idx (0..47) covers row idx/3, 256-f32 third idx%3.
#define STAGE(bufi, tile) do {                                                \
        float* vb_ = vst + (bufi) * (TT * VROW);                              \
        _Pragma("unroll")                                                     \
        for (int i_ = 0; i_ < 6; ++i_) {                                      \
            const int idx_ = w * 6 + i_;                                      \
            const int r_ = idx_ / 3, c_ = idx_ % 3;                           \
            gl_lds(&x[(xbase + (size_t)(tile) * TT + r_) * DD + c_ * 256 + lane * 4], \
                   vb_ + r_ * VROW + c_ * 256);                               \
        }                                                                     \
    } while (0)

    STAGE(0, 0);

    const float scale = 0.036084391824351615f;  // 768^-0.5
    const int p_  = t >> 3;      // softmax row
    const int np_ = t & 7;       // softmax n-pair

    for (int tile = 0; tile < NTILE; ++tile) {
        if (tile < NTILE - 1) { STAGE((tile + 1) & 1, tile + 1); S_WAITCNT_VM(6); }
        else                  { S_WAITCNT_VM(0); }
        BARRIER();
        const float* vb = vst + (tile & 1) * (TT * VROW);

        // ---- QK^T: wave w: kd in {w*96, +32, +64}, all 4 p-frags ----
        f32x4 acc[4] = {};
        #pragma unroll
        for (int s = 0; s < 3; ++s) {
            const int g0 = w * 24 + s * 8 + hi * 2;      // f32x4 granule index
            const float* kp = vb + l15 * VROW + g0 * 4;
            const f32x4 lo = *(const f32x4*)kp;
            const f32x4 hg = *(const f32x4*)(kp + 4);
            const bf16x8 kf = {(__bf16)lo[0], (__bf16)lo[1], (__bf16)lo[2], (__bf16)lo[3],
                               (__bf16)hg[0], (__bf16)hg[1], (__bf16)hg[2], (__bf16)hg[3]};
            #pragma unroll
            for (int am = 0; am < 4; ++am) acc[am] = mfma16(qf[am][s], kf, acc[am]);
        }
        #pragma unroll
        for (int am = 0; am < 4; ++am)
            #pragma unroll
            for (int j = 0; j < 4; ++j)
                lpf[(w * 64 + am * 16 + hi * 4 + j) * 18 + l15] = acc[am][j];
        LDS_BARRIER();

        // ---- online softmax: 8 threads per p-row, 2 tokens each ----
        float s0 = 0.f, s1 = 0.f;
        #pragma unroll
        for (int sl = 0; sl < 8; ++sl) {
            const float2 v2 = *(const float2*)&lpf[(sl * 64 + p_) * 18 + 2 * np_];
            s0 += v2.x; s1 += v2.y;
        }
        s0 *= scale; s1 *= scale;
        float mt = fmaxf(s0, s1);
        mt = fmaxf(mt, __shfl_xor(mt, 1));
        mt = fmaxf(mt, __shfl_xor(mt, 2));
        mt = fmaxf(mt, __shfl_xor(mt, 4));
        const float mo = mrun[p_];
        const float mn = fmaxf(mo, mt);
        const float e0 = __expf(s0 - mn), e1 = __expf(s1 - mn);
        float lsum = e0 + e1;
        lsum += __shfl_xor(lsum, 1);
        lsum += __shfl_xor(lsum, 2);
        lsum += __shfl_xor(lsum, 4);
        *(bf16x2*)&pbuf[p_ * PSTRIDE + 2 * np_] = (bf16x2){(__bf16)e0, (__bf16)e1};
        if (np_ == 0) {
            const float f = __expf(mo - mn);   // == 1.0 exactly when mt <= mo
            lrun[p_] = lrun[p_] * f + lsum;
            mrun[p_] = mn;
            rsc[p_]  = f;
        }
        LDS_BARRIER();

        // ---- O-rescale (explicit f32x4 rsc load; addresses contiguous) ----
        #pragma unroll
        for (int am = 0; am < 4; ++am) {
            const f32x4 f4 = *(const f32x4*)&rsc[am * 16 + hi * 4];
            #pragma unroll
            for (int j = 0; j < 4; ++j)
                #pragma unroll
                for (int df = 0; df < 6; ++df) O[am][df][j] *= f4[j];
        }

#if HAVE_K16
        // ---- PV via K=16 MFMA, vectorized V reads (DMAP remap) ----
        s16x4 pf[4];
        #pragma unroll
        for (int am = 0; am < 4; ++am)
            pf[am] = *(const s16x4*)&pbuf[(am * 16 + l15) * PSTRIDE + hi * 4];
        f32x4 va[4];
        f32x2 vc[4];
        #pragma unroll
        for (int i = 0; i < 4; ++i) {
            const float* g0 = vb + (hi * 4 + i) * VROW + w * 96;
            va[i] = *(const f32x4*)(g0 + l15 * 4);
            vc[i] = *(const f32x2*)(g0 + 64 + l15 * 2);
        }
        #pragma unroll
        for (int df = 0; df < 4; ++df) {
            s16x4 vfr;
            #pragma unroll
            for (int i = 0; i < 4; ++i) vfr[i] = bf2s(va[i][df]);
            #pragma unroll
            for (int am = 0; am < 4; ++am)
                O[am][df] = __builtin_amdgcn_mfma_f32_16x16x16bf16_1k(pf[am], vfr, O[am][df], 0, 0, 0);
        }
        #pragma unroll
        for (int df = 4; df < 6; ++df) {
            s16x4 vfr;
            #pragma unroll
            for (int i = 0; i < 4; ++i) vfr[i] = bf2s(vc[i][df - 4]);
            #pragma unroll
            for (int am = 0; am < 4; ++am)
                O[am][df] = __builtin_amdgcn_mfma_f32_16x16x16bf16_1k(pf[am], vfr, O[am][df], 0, 0, 0);
        }
#else
        // ---- fallback: K=32 MFMA (zero-padded upper half), DMAP-consistent ----
        bf16x8 pf[4];
        #pragma unroll
        for (int am = 0; am < 4; ++am)
            pf[am] = *(const bf16x8*)&pbuf[(am * 16 + l15) * PSTRIDE + hi * 8];
        #pragma unroll
        for (int df = 0; df < 6; ++df) {
            float vf[8];
            #pragma unroll
            for (int i = 0; i < 8; ++i) {
                const int k_ = (hi * 8 + i) & 15;
                vf[i] = vb[k_ * VROW + w * 96 + DMAP(l15, df)];
            }
            const bf16x8 vfr = {(__bf16)vf[0], (__bf16)vf[1], (__bf16)vf[2], (__bf16)vf[3],
                                (__bf16)vf[4], (__bf16)vf[5], (__bf16)vf[6], (__bf16)vf[7]};
            #pragma unroll
            for (int am = 0; am < 4; ++am) O[am][df] = mfma16(pf[am], vfr, O[am][df]);
        }
#endif
        LDS_BARRIER();
    }

    // ---- epilogue: stats + unnormalized O to part (f16), DMAP d-indexing ----
    if (t < 64) {
        const size_t si = ((size_t)b * 16 + sp) * 64 + t;
        statm[si] = mrun[t];
        statl[si] = lrun[t];
    }
    #pragma unroll
    for (int am = 0; am < 4; ++am)
        #pragma unroll
        for (int j = 0; j < 4; ++j) {
            const int p = am * 16 + hi * 4 + j;
            #pragma unroll
            for (int df = 0; df < 6; ++df) {
                const int d_ = w * 96 + DMAP(l15, df);
                part[(((size_t)sp * BB + b) * PP + p) * DD + d_] = (_Float16)O[am][df][j];
            }
        }
}

// ---------------------------------------------------------------------------
// Combine: out[b,p,d] = sum_sp exp(m_sp - M) * part[sp,b,p,d] / D,
//          D = sum_c exp(m_c - M) * l_c.
// ---------------------------------------------------------------------------
__global__ __launch_bounds__(256) void k_combine(const _Float16* __restrict__ part,
                                                 const float* __restrict__ statm,
                                                 const float* __restrict__ statl,
                                                 float* __restrict__ out) {
    const size_t idx = (size_t)blockIdx.x * 256 + threadIdx.x;  // f32x4 units
    const size_t e = idx * 4;
    const int bp = (int)(e / DD);
    const int b = bp >> 6, p = bp & 63;

    float M = -1e30f;
    #pragma unroll
    for (int c = 0; c < 16; ++c) M = fmaxf(M, statm[((size_t)b * 16 + c) * 64 + p]);
    float Ee[16];
    float D = 0.f;
    #pragma unroll
    for (int c = 0; c < 16; ++c) {
        Ee[c] = __expf(statm[((size_t)b * 16 + c) * 64 + p] - M);
        D += Ee[c] * statl[((size_t)b * 16 + c) * 64 + p];
    }
    const float inv = 1.f / D;

    float4 v = {0.f, 0.f, 0.f, 0.f};
    #pragma unroll
    for (int c = 0; c < 16; ++c) {
        const f16x4 h = *(const f16x4*)&part[(size_t)c * ((size_t)BB * PP * DD) + e];
        v.x += Ee[c] * (float)h[0];
        v.y += Ee[c] * (float)h[1];
        v.z += Ee[c] * (float)h[2];
        v.w += Ee[c] * (float)h[3];
    }
    v.x *= inv; v.y *= inv; v.z *= inv; v.w *= inv;
    *(float4*)&out[e] = v;
}

extern "C" void kernel_launch(void* const* d_in, const int* in_sizes, int n_in,
                              void* d_out, int out_size, void* d_ws, size_t ws_size,
                              hipStream_t stream) {
    const float* x = (const float*)d_in[0];   // [16, 4096, 768]
    const float* q = (const float*)d_in[1];   // [16, 64, 768]
    float* out = (float*)d_out;               // [16, 64, 768]

    char* ws = (char*)d_ws;
    float*     statm = (float*)ws;                       // 64 KB [16][16][64]
    float*     statl = (float*)(ws + 65536);             // 64 KB
    _Float16*  part  = (_Float16*)(ws + 131072);         // 24 MB [16][16][64][768]

    hipLaunchKernelGGL(k_flash,   dim3(256), dim3(512), 0, stream, x, q, statm, statl, part);
    hipLaunchKernelGGL(k_combine, dim3(768), dim3(256), 0, stream, part, statm, statl, out);
}